// Round 1
// baseline (27863.297 us; speedup 1.0000x reference)
//
#include <hip/hip_runtime.h>
#include <hip/hip_bf16.h>
#include <stdint.h>

#define VV 1000
#define EE 1024
#define DD 512
#define AA 512
#define TT 128
#define BB 128
#define PP 196
#define SS 256

typedef unsigned short ushort_t;
typedef __attribute__((ext_vector_type(8))) short short8;
typedef __attribute__((ext_vector_type(4))) float floatx4;
typedef __attribute__((ext_vector_type(4))) unsigned short ushort4_t;
typedef __attribute__((ext_vector_type(8))) unsigned short ushort8_t;

__device__ __forceinline__ float bf2f(unsigned short h) {
    return __uint_as_float(((unsigned int)h) << 16);
}
__device__ __forceinline__ unsigned short f2bf(float x) {
    unsigned int u = __float_as_uint(x);
    unsigned int r = (u + 0x7fffu + ((u >> 16) & 1u)) >> 16;
    return (unsigned short)r;
}
__device__ __forceinline__ float sigmoidf_(float x) { return 1.f / (1.f + __expf(-x)); }
__device__ __forceinline__ float tanhf_(float x) {
    // 1 - 2/(e^{2x}+1): saturates correctly at +/-inf without NaN
    float e = __expf(2.f * x);
    return 1.f - 2.f / (e + 1.f);
}

// ---------------- one-time prep kernels ----------------

__global__ void cvt_kernel(const float* __restrict__ src, ushort_t* __restrict__ dst, int n) {
    int i = blockIdx.x * 256 + threadIdx.x;
    if (i < n) dst[i] = f2bf(src[i]);
}

__global__ void mean_kernel(const float* __restrict__ feat, float* __restrict__ meanv) {
    int idx = blockIdx.x * 256 + threadIdx.x;  // 131072 = 128*1024
    int b = idx >> 10;
    int e = idx & 1023;
    const float* p = feat + (size_t)b * PP * 1024 + e;
    float s = 0.f;
    for (int pp = 0; pp < PP; ++pp) s += p[(size_t)pp * 1024];
    meanv[idx] = s * (1.f / 196.f);
}

__global__ __launch_bounds__(256) void init_kernel(
    const float* __restrict__ meanv, const float* __restrict__ Wh0, const float* __restrict__ bh0,
    const float* __restrict__ Wc0, const float* __restrict__ bc0,
    float* __restrict__ c1, float* __restrict__ c2,
    ushort_t* __restrict__ h1b, ushort_t* __restrict__ h2b) {
    int b = blockIdx.x, t = threadIdx.x;
    __shared__ float ml[1024];
    for (int i = t; i < 1024; i += 256) ml[i] = meanv[b * 1024 + i];
    __syncthreads();
    for (int d = t; d < 512; d += 256) {
        const float4* wh = (const float4*)(Wh0 + (size_t)d * 1024);
        const float4* wc = (const float4*)(Wc0 + (size_t)d * 1024);
        float ah = bh0[d], ac = bc0[d];
        #pragma unroll 4
        for (int j = 0; j < 256; ++j) {
            float4 w = wh[j];
            ah += w.x * ml[4 * j] + w.y * ml[4 * j + 1] + w.z * ml[4 * j + 2] + w.w * ml[4 * j + 3];
        }
        #pragma unroll 4
        for (int j = 0; j < 256; ++j) {
            float4 w = wc[j];
            ac += w.x * ml[4 * j] + w.y * ml[4 * j + 1] + w.z * ml[4 * j + 2] + w.w * ml[4 * j + 3];
        }
        c1[b * 512 + d] = ac;
        c2[b * 512 + d] = ac;
        ushort_t hb = f2bf(ah);
        h1b[b * 512 + d] = hb;
        h2b[b * 512 + d] = hb;
    }
}

// enc_t = features @ Wenc^T + benc, stored bf16.  M=25088, N=512, K=1024.
__global__ __launch_bounds__(256) void enc_gemm(
    const ushort_t* __restrict__ feat_bf, const ushort_t* __restrict__ wenc_bf,
    const float* __restrict__ benc, ushort_t* __restrict__ enc_bf) {
    const int t = threadIdx.x, blk = blockIdx.x;
    const int bm = (blk % 392) * 64, bn = (blk / 392) * 64;
    const int lane = t & 63, wv = t >> 6;
    const int n = lane & 15, q = lane >> 4;
    const int arow = bm + wv * 16 + n;
    const short8* ap = (const short8*)(feat_bf + (size_t)arow * 1024 + q * 8);
    const short8* bp0 = (const short8*)(wenc_bf + (size_t)(bn + 0 * 16 + n) * 1024 + q * 8);
    const short8* bp1 = (const short8*)(wenc_bf + (size_t)(bn + 1 * 16 + n) * 1024 + q * 8);
    const short8* bp2 = (const short8*)(wenc_bf + (size_t)(bn + 2 * 16 + n) * 1024 + q * 8);
    const short8* bp3 = (const short8*)(wenc_bf + (size_t)(bn + 3 * 16 + n) * 1024 + q * 8);
    floatx4 acc0 = {0.f, 0.f, 0.f, 0.f}, acc1 = acc0, acc2 = acc0, acc3 = acc0;
    for (int ks = 0; ks < 32; ++ks) {
        short8 a8 = ap[ks * 4];
        acc0 = __builtin_amdgcn_mfma_f32_16x16x32_bf16(a8, bp0[ks * 4], acc0, 0, 0, 0);
        acc1 = __builtin_amdgcn_mfma_f32_16x16x32_bf16(a8, bp1[ks * 4], acc1, 0, 0, 0);
        acc2 = __builtin_amdgcn_mfma_f32_16x16x32_bf16(a8, bp2[ks * 4], acc2, 0, 0, 0);
        acc3 = __builtin_amdgcn_mfma_f32_16x16x32_bf16(a8, bp3[ks * 4], acc3, 0, 0, 0);
    }
    #pragma unroll
    for (int r = 0; r < 4; ++r) {
        int m = bm + wv * 16 + q * 4 + r;
        int a0 = bn + n;
        enc_bf[(size_t)m * 512 + a0] = f2bf(acc0[r] + benc[a0]);
        enc_bf[(size_t)m * 512 + a0 + 16] = f2bf(acc1[r] + benc[a0 + 16]);
        enc_bf[(size_t)m * 512 + a0 + 32] = f2bf(acc2[r] + benc[a0 + 32]);
        enc_bf[(size_t)m * 512 + a0 + 48] = f2bf(acc3[r] + benc[a0 + 48]);
    }
}

// ---------------- per-step kernels ----------------

// blocks 0..127: per-batch dec_t matvec + attention + softmax + awe + x1 build (step s)
// blocks 128..190: vocab projection preds[s-1] = h2 @ Wf^T + bf (MFMA)
__global__ __launch_bounds__(256) void step_attn_preds(
    const ushort_t* __restrict__ enc_bf, const ushort_t* __restrict__ feat_bf,
    const ushort_t* __restrict__ wdec_bf, const ushort_t* __restrict__ wf_bf,
    const ushort_t* __restrict__ emb_bf, ushort_t* __restrict__ x1_bf,
    const ushort_t* __restrict__ h2cur, const int* __restrict__ latexes,
    const float* __restrict__ wattn, const float* __restrict__ battn,
    const float* __restrict__ bdec, const float* __restrict__ bfv,
    float* __restrict__ out, int s) {
    const int t = threadIdx.x;
    const int blk = blockIdx.x;
    if (blk < BB) {
        if (s >= SS) return;
        const int b = blk;
        __shared__ float dec_lds[512];
        __shared__ float wa_lds[512];
        __shared__ float h2row[512];
        __shared__ float red[256];
        __shared__ float attn_lds[256];
        __shared__ float alpha_lds[200];
        for (int i = t; i < 512; i += 256) {
            h2row[i] = bf2f(h2cur[b * 512 + i]);
            wa_lds[i] = wattn[i];
        }
        __syncthreads();
        // dec_t[b,:] = Wdec @ h2[b] + bdec
        for (int d = t; d < 512; d += 256) {
            const ushort8_t* wr = (const ushort8_t*)(wdec_bf + (size_t)d * 512);
            float acc = 0.f;
            #pragma unroll 4
            for (int j = 0; j < 64; ++j) {
                ushort8_t w8 = wr[j];
                const float* h8 = &h2row[j * 8];
                #pragma unroll
                for (int u = 0; u < 8; ++u) acc += bf2f(w8[u]) * h8[u];
            }
            dec_lds[d] = acc + bdec[d];
        }
        __syncthreads();
        // logits: attn[p] = wa . tanh(enc[b,p,:] + dec) + ba
        const int wv = t >> 6, lane = t & 63;
        for (int p = wv; p < PP; p += 4) {
            const ushort8_t ev = *(const ushort8_t*)(enc_bf + ((size_t)(b * PP + p)) * 512 + lane * 8);
            float acc = 0.f;
            #pragma unroll
            for (int u = 0; u < 8; ++u) {
                float x = bf2f(ev[u]) + dec_lds[lane * 8 + u];
                acc += wa_lds[lane * 8 + u] * tanhf_(x);
            }
            #pragma unroll
            for (int off = 32; off > 0; off >>= 1) acc += __shfl_xor(acc, off, 64);
            if (lane == 0) attn_lds[p] = acc + battn[0];
        }
        __syncthreads();
        // softmax over 196
        float logit = (t < PP) ? attn_lds[t] : -1e30f;
        red[t] = logit;
        __syncthreads();
        for (int st = 128; st > 0; st >>= 1) {
            if (t < st) red[t] = fmaxf(red[t], red[t + st]);
            __syncthreads();
        }
        float mx = red[0];
        __syncthreads();
        float e = (t < PP) ? __expf(logit - mx) : 0.f;
        red[t] = e;
        __syncthreads();
        for (int st = 128; st > 0; st >>= 1) {
            if (t < st) red[t] += red[t + st];
            __syncthreads();
        }
        float inv = 1.f / red[0];
        float a = e * inv;
        if (t < PP) {
            alpha_lds[t] = a;
            out[(size_t)32768000 + (size_t)b * 50176 + (size_t)s * 196 + t] = a;
        }
        __syncthreads();
        // awe[b,e] = sum_p alpha[p] * features[b,p,e]; write x1 = [emb | awe] in bf16
        float a0 = 0.f, a1 = 0.f, a2 = 0.f, a3 = 0.f;
        const int e0 = t * 4;
        for (int p = 0; p < PP; ++p) {
            float av = alpha_lds[p];
            ushort4_t f4 = *(const ushort4_t*)(feat_bf + ((size_t)(b * PP + p)) * 1024 + e0);
            a0 += av * bf2f(f4[0]);
            a1 += av * bf2f(f4[1]);
            a2 += av * bf2f(f4[2]);
            a3 += av * bf2f(f4[3]);
        }
        ushort4_t o4;
        o4[0] = f2bf(a0); o4[1] = f2bf(a1); o4[2] = f2bf(a2); o4[3] = f2bf(a3);
        *(ushort4_t*)(x1_bf + (size_t)b * 1152 + 128 + e0) = o4;
        if (t < TT) {
            int tok = latexes[b * 257 + s];
            x1_bf[(size_t)b * 1152 + t] = emb_bf[tok * TT + t];
        }
    } else {
        // preds[s-1] = h2 @ Wf^T + bf  ([128 x 1000], K=512)
        if (s == 0) return;
        const int wg2 = blk - BB;  // 0..62
        const int v0 = wg2 * 16;
        const int lane = t & 63, wv = t >> 6;
        const int n = lane & 15, q = lane >> 4;
        const int vrow = v0 + n;
        const int vclamp = vrow < VV ? vrow : VV - 1;
        const short8* bp = (const short8*)(wf_bf + (size_t)vclamp * 512 + q * 8);
        const int m0 = 2 * wv * 16 + n;
        const short8* ap0 = (const short8*)(h2cur + (size_t)m0 * 512 + q * 8);
        const short8* ap1 = (const short8*)(h2cur + (size_t)(m0 + 16) * 512 + q * 8);
        floatx4 acc0 = {0.f, 0.f, 0.f, 0.f}, acc1 = acc0;
        for (int ks = 0; ks < 16; ++ks) {
            short8 b8 = bp[ks * 4];
            acc0 = __builtin_amdgcn_mfma_f32_16x16x32_bf16(ap0[ks * 4], b8, acc0, 0, 0, 0);
            acc1 = __builtin_amdgcn_mfma_f32_16x16x32_bf16(ap1[ks * 4], b8, acc1, 0, 0, 0);
        }
        if (vrow < VV) {
            float cb = bfv[vrow];
            size_t so = (size_t)(s - 1) * 1000 + vrow;
            #pragma unroll
            for (int r = 0; r < 4; ++r) {
                int br = 2 * wv * 16 + q * 4 + r;
                out[(size_t)br * 256000 + so] = acc0[r] + cb;
                out[(size_t)(br + 16) * 256000 + so] = acc1[r] + cb;
            }
        }
    }
}

// One LSTM cell: gates = A1 @ Wih^T + A2 @ Whh^T + bih + bhh; update c in place; write h (bf16).
// Each WG owns 4 d-columns (x 4 gates = 16 MFMA cols) for all 128 batches.
__global__ __launch_bounds__(256) void lstm_cell_kernel(
    const ushort_t* __restrict__ A1, int k1, const ushort_t* __restrict__ Wih,
    const ushort_t* __restrict__ A2, const ushort_t* __restrict__ Whh,
    const float* __restrict__ bih, const float* __restrict__ bhh,
    float* __restrict__ cst, ushort_t* __restrict__ hout) {
    const int t = threadIdx.x, wg = blockIdx.x;
    const int d0 = wg * 4;
    const int lane = t & 63, wv = t >> 6;
    const int n = lane & 15, q = lane >> 4;
    const int col = (n >> 2) * 512 + d0 + (n & 3);  // global gate column
    const int m0 = 2 * wv * 16 + n;
    floatx4 acc0 = {0.f, 0.f, 0.f, 0.f}, acc1 = acc0;
    {
        const short8* bp = (const short8*)(Wih + (size_t)col * k1 + q * 8);
        const short8* a0 = (const short8*)(A1 + (size_t)m0 * k1 + q * 8);
        const short8* a1 = (const short8*)(A1 + (size_t)(m0 + 16) * k1 + q * 8);
        const int nk = k1 >> 5;
        for (int ks = 0; ks < nk; ++ks) {
            short8 b8 = bp[ks * 4];
            acc0 = __builtin_amdgcn_mfma_f32_16x16x32_bf16(a0[ks * 4], b8, acc0, 0, 0, 0);
            acc1 = __builtin_amdgcn_mfma_f32_16x16x32_bf16(a1[ks * 4], b8, acc1, 0, 0, 0);
        }
    }
    {
        const short8* bp = (const short8*)(Whh + (size_t)col * 512 + q * 8);
        const short8* a0 = (const short8*)(A2 + (size_t)m0 * 512 + q * 8);
        const short8* a1 = (const short8*)(A2 + (size_t)(m0 + 16) * 512 + q * 8);
        for (int ks = 0; ks < 16; ++ks) {
            short8 b8 = bp[ks * 4];
            acc0 = __builtin_amdgcn_mfma_f32_16x16x32_bf16(a0[ks * 4], b8, acc0, 0, 0, 0);
            acc1 = __builtin_amdgcn_mfma_f32_16x16x32_bf16(a1[ks * 4], b8, acc1, 0, 0, 0);
        }
    }
    __shared__ float glds[128][16];
    #pragma unroll
    for (int r = 0; r < 4; ++r) {
        glds[2 * wv * 16 + q * 4 + r][n] = acc0[r];
        glds[2 * wv * 16 + 16 + q * 4 + r][n] = acc1[r];
    }
    __syncthreads();
    for (int idx = t; idx < 512; idx += 256) {
        int bb = idx >> 2, dj = idx & 3;
        int d = d0 + dj;
        float gi = glds[bb][dj] + bih[d] + bhh[d];
        float gf = glds[bb][4 + dj] + bih[512 + d] + bhh[512 + d];
        float gg = glds[bb][8 + dj] + bih[1024 + d] + bhh[1024 + d];
        float go = glds[bb][12 + dj] + bih[1536 + d] + bhh[1536 + d];
        float co = cst[bb * 512 + d];
        float cn = sigmoidf_(gf) * co + sigmoidf_(gi) * tanhf_(gg);
        float hn = sigmoidf_(go) * tanhf_(cn);
        cst[bb * 512 + d] = cn;
        hout[bb * 512 + d] = f2bf(hn);
    }
}

extern "C" void kernel_launch(void* const* d_in, const int* in_sizes, int n_in,
                              void* d_out, int out_size, void* d_ws, size_t ws_size,
                              hipStream_t stream) {
    const float* features = (const float*)d_in[0];
    const int* latexes = (const int*)d_in[1];
    const float* emb = (const float*)d_in[2];
    const float* Wenc = (const float*)d_in[3];
    const float* benc = (const float*)d_in[4];
    const float* Wdec = (const float*)d_in[5];
    const float* bdec = (const float*)d_in[6];
    const float* Wattn = (const float*)d_in[7];
    const float* battn = (const float*)d_in[8];
    const float* W1ih = (const float*)d_in[9];
    const float* W1hh = (const float*)d_in[10];
    const float* b1ih = (const float*)d_in[11];
    const float* b1hh = (const float*)d_in[12];
    const float* W2ih = (const float*)d_in[13];
    const float* W2hh = (const float*)d_in[14];
    const float* b2ih = (const float*)d_in[15];
    const float* b2hh = (const float*)d_in[16];
    const float* Wh0 = (const float*)d_in[17];
    const float* bh0 = (const float*)d_in[18];
    const float* Wc0 = (const float*)d_in[19];
    const float* bc0 = (const float*)d_in[20];
    const float* Wf = (const float*)d_in[23];
    const float* bfv = (const float*)d_in[24];
    float* out = (float*)d_out;

    char* ws = (char*)d_ws;
    size_t off = 0;
    auto alloc = [&](size_t bytes) {
        void* p = ws + off;
        off += (bytes + 255) & ~(size_t)255;
        return p;
    };
    ushort_t* feat_bf = (ushort_t*)alloc(25690112ull * 2);
    ushort_t* enc_bf = (ushort_t*)alloc(12845056ull * 2);
    ushort_t* w1ih_bf = (ushort_t*)alloc(2359296ull * 2);
    ushort_t* w1hh_bf = (ushort_t*)alloc(1048576ull * 2);
    ushort_t* w2ih_bf = (ushort_t*)alloc(1048576ull * 2);
    ushort_t* w2hh_bf = (ushort_t*)alloc(1048576ull * 2);
    ushort_t* wf_bf = (ushort_t*)alloc(512000ull * 2);
    ushort_t* wdec_bf = (ushort_t*)alloc(262144ull * 2);
    ushort_t* wenc_bf = (ushort_t*)alloc(524288ull * 2);
    ushort_t* emb_bf = (ushort_t*)alloc(128000ull * 2);
    float* meanv = (float*)alloc(131072ull * 4);
    float* c1 = (float*)alloc(65536ull * 4);
    float* c2 = (float*)alloc(65536ull * 4);
    ushort_t* h1b0 = (ushort_t*)alloc(65536ull * 2);
    ushort_t* h1b1 = (ushort_t*)alloc(65536ull * 2);
    ushort_t* h2b0 = (ushort_t*)alloc(65536ull * 2);
    ushort_t* h2b1 = (ushort_t*)alloc(65536ull * 2);
    ushort_t* x1_bf = (ushort_t*)alloc(147456ull * 2);
    ushort_t* h1b[2] = {h1b0, h1b1};
    ushort_t* h2b[2] = {h2b0, h2b1};

    auto cv = [&](const float* s, ushort_t* d, int n) {
        cvt_kernel<<<(n + 255) / 256, 256, 0, stream>>>(s, d, n);
    };
    cv(features, feat_bf, 25690112);
    cv(Wenc, wenc_bf, 524288);
    cv(W1ih, w1ih_bf, 2359296);
    cv(W1hh, w1hh_bf, 1048576);
    cv(W2ih, w2ih_bf, 1048576);
    cv(W2hh, w2hh_bf, 1048576);
    cv(Wf, wf_bf, 512000);
    cv(Wdec, wdec_bf, 262144);
    cv(emb, emb_bf, 128000);
    mean_kernel<<<512, 256, 0, stream>>>(features, meanv);
    init_kernel<<<128, 256, 0, stream>>>(meanv, Wh0, bh0, Wc0, bc0, c1, c2, h1b[0], h2b[0]);
    enc_gemm<<<3136, 256, 0, stream>>>(feat_bf, wenc_bf, benc, enc_bf);

    for (int s = 0; s <= SS; ++s) {
        int cur = s & 1, nxt = 1 - cur;
        step_attn_preds<<<191, 256, 0, stream>>>(enc_bf, feat_bf, wdec_bf, wf_bf, emb_bf, x1_bf,
                                                 h2b[cur], latexes, Wattn, battn, bdec, bfv, out, s);
        if (s < SS) {
            lstm_cell_kernel<<<128, 256, 0, stream>>>(x1_bf, 1152, w1ih_bf, h1b[cur], w1hh_bf,
                                                      b1ih, b1hh, c1, h1b[nxt]);
            lstm_cell_kernel<<<128, 256, 0, stream>>>(h1b[nxt], 512, w2ih_bf, h2b[cur], w2hh_bf,
                                                      b2ih, b2hh, c2, h2b[nxt]);
        }
    }
}